// Round 2
// baseline (3097.950 us; speedup 1.0000x reference)
//
#include <hip/hip_runtime.h>
#include <math.h>

#define HW 65536
#define NPOS 262144   // B*HW

__device__ __forceinline__ float gelu_exact(float v){
    return 0.5f * v * (1.0f + erff(v * 0.70710678118654752f));
}
__device__ __forceinline__ float sigmoid_(float v){
    return 1.0f / (1.0f + __expf(-v));
}

// ---------------------------------------------------------------------------
// K1: LN1(ref) -> 1x1 w_kv (k_pre,v_pre) ; LN3(x) -> 1x1 w_q (q_pre)
// Block 0 also zeroes the small accumulator region (dots/sqq/sqk).
// ---------------------------------------------------------------------------
__global__ __launch_bounds__(256) void k_ln_1x1(
    const float* __restrict__ x, const float* __restrict__ ref,
    const float* __restrict__ ln1w, const float* __restrict__ ln1b,
    const float* __restrict__ ln3w, const float* __restrict__ ln3b,
    const float* __restrict__ wkv, const float* __restrict__ wq,
    float* __restrict__ kpre, float* __restrict__ vpre, float* __restrict__ qpre,
    float* __restrict__ zbuf)
{
    __shared__ float s_wkv[128*64];
    __shared__ float s_wq[64*64];
    __shared__ float s_l1w[64], s_l1b[64], s_l3w[64], s_l3b[64];
    int t = threadIdx.x;
    if (blockIdx.x == 0){
        for (int j = t; j < 4608; j += 256) zbuf[j] = 0.f;
    }
    for (int j = t; j < 128*64; j += 256) s_wkv[j] = wkv[j];
    for (int j = t; j < 64*64;  j += 256) s_wq[j]  = wq[j];
    if (t < 64){ s_l1w[t]=ln1w[t]; s_l1b[t]=ln1b[t]; s_l3w[t]=ln3w[t]; s_l3b[t]=ln3b[t]; }
    __syncthreads();

    unsigned gid = blockIdx.x * 256u + t;
    unsigned b = gid >> 16, pos = gid & 65535u;
    const size_t base = (size_t)b * 64 * HW + pos;

    float v[64];
    // ---- phase A: ref -> LN1 -> kv 1x1 ----
    float s = 0.f, ss = 0.f;
    #pragma unroll
    for (int c = 0; c < 64; c++){ float r = ref[base + (size_t)c*HW]; v[c] = r; s += r; ss += r*r; }
    float mu  = s * (1.0f/64.0f);
    float var = ss * (1.0f/64.0f) - mu*mu;
    float inv = rsqrtf(var + 1e-5f);
    #pragma unroll
    for (int c = 0; c < 64; c++) v[c] = (v[c]-mu)*inv*s_l1w[c] + s_l1b[c];
    for (int oc = 0; oc < 64; oc++){
        float a = 0.f, a2 = 0.f;
        #pragma unroll
        for (int c = 0; c < 64; c++){
            a  += s_wkv[oc*64 + c]       * v[c];
            a2 += s_wkv[(oc+64)*64 + c]  * v[c];
        }
        kpre[(size_t)(b*64+oc)*HW + pos] = a;
        vpre[(size_t)(b*64+oc)*HW + pos] = a2;
    }
    // ---- phase B: x -> LN3 -> q 1x1 ----
    s = 0.f; ss = 0.f;
    #pragma unroll
    for (int c = 0; c < 64; c++){ float r = x[base + (size_t)c*HW]; v[c] = r; s += r; ss += r*r; }
    mu  = s * (1.0f/64.0f);
    var = ss * (1.0f/64.0f) - mu*mu;
    inv = rsqrtf(var + 1e-5f);
    #pragma unroll
    for (int c = 0; c < 64; c++) v[c] = (v[c]-mu)*inv*s_l3w[c] + s_l3b[c];
    for (int oc = 0; oc < 64; oc++){
        float a = 0.f;
        #pragma unroll
        for (int c = 0; c < 64; c++) a += s_wq[oc*64 + c] * v[c];
        qpre[(size_t)(b*64+oc)*HW + pos] = a;
    }
}

// ---------------------------------------------------------------------------
// K2: depthwise 3x3, pad 1. w9 indexed by [ch*9+k] (caller offsets base ptr).
// ---------------------------------------------------------------------------
__global__ __launch_bounds__(256) void k_dw3x3(
    const float* __restrict__ in, const float* __restrict__ w9,
    float* __restrict__ out)
{
    __shared__ float s_in[10*35];
    int t  = threadIdx.x;
    int b  = blockIdx.z >> 6, ch = blockIdx.z & 63;
    int x0 = blockIdx.x * 32, y0 = blockIdx.y * 8;
    const float* src = in + (size_t)(b*64+ch)*HW;
    for (int j = t; j < 340; j += 256){
        int r = j / 34, cc = j - r*34;
        int gy = y0 - 1 + r, gx = x0 - 1 + cc;
        float val = 0.f;
        if (gy >= 0 && gy < 256 && gx >= 0 && gx < 256) val = src[gy*256 + gx];
        s_in[r*35 + cc] = val;
    }
    float w[9];
    #pragma unroll
    for (int k = 0; k < 9; k++) w[k] = w9[ch*9 + k];
    __syncthreads();
    int ty = t >> 5, tx = t & 31;
    float a = 0.f;
    #pragma unroll
    for (int ky = 0; ky < 3; ky++)
        #pragma unroll
        for (int kx = 0; kx < 3; kx++)
            a += w[ky*3+kx] * s_in[(ty+ky)*35 + tx+kx];
    out[(size_t)(b*64+ch)*HW + (y0+ty)*256 + x0+tx] = a;
}

// ---------------------------------------------------------------------------
// K3: q.kT dots (per head 16x16) + per-channel sum-of-squares, via LDS tiles
// and atomicAdd partial reduction. 256 blocks = 4 batches x 64 pixel chunks.
// ---------------------------------------------------------------------------
__global__ __launch_bounds__(256) void k_qk_dots(
    const float* __restrict__ q, const float* __restrict__ k,
    float* __restrict__ dots, float* __restrict__ sqq, float* __restrict__ sqk)
{
    __shared__ float qs[64*65];
    __shared__ float ks[64*65];
    int t = threadIdx.x;
    int b = blockIdx.x >> 6;
    int p0 = (blockIdx.x & 63) * 1024;
    int plane = t & 63, cb = t >> 6;
    int h = t >> 6, cq = (t >> 2) & 15, ck0 = (t & 3) << 2;
    int cQ = h*16 + cq, cK = h*16 + ck0;
    float acc0=0,acc1=0,acc2=0,acc3=0, sacc=0;

    for (int sblk = 0; sblk < 16; sblk++){
        __syncthreads();
        int pbase = p0 + sblk*64;
        for (int i = 0; i < 16; i++){
            int c = cb + 4*i;
            qs[plane*65 + c] = q[(size_t)(b*64+c)*HW + pbase + plane];
            ks[plane*65 + c] = k[(size_t)(b*64+c)*HW + pbase + plane];
        }
        __syncthreads();
        for (int p = 0; p < 64; p++){
            float qv = qs[p*65 + cQ];
            acc0 += qv * ks[p*65 + cK + 0];
            acc1 += qv * ks[p*65 + cK + 1];
            acc2 += qv * ks[p*65 + cK + 2];
            acc3 += qv * ks[p*65 + cK + 3];
        }
        if (t < 64){
            for (int p = 0; p < 64; p++){ float vv = qs[p*65 + t]; sacc += vv*vv; }
        } else if (t < 128){
            int c = t - 64;
            for (int p = 0; p < 64; p++){ float vv = ks[p*65 + c]; sacc += vv*vv; }
        }
    }
    int dbase = ((b*4 + h)*16 + cq)*16 + ck0;
    atomicAdd(&dots[dbase+0], acc0);
    atomicAdd(&dots[dbase+1], acc1);
    atomicAdd(&dots[dbase+2], acc2);
    atomicAdd(&dots[dbase+3], acc3);
    if (t < 64)       atomicAdd(&sqq[b*64 + t], sacc);
    else if (t < 128) atomicAdd(&sqk[b*64 + t - 64], sacc);
}

// ---------------------------------------------------------------------------
// K4: scale by 1/(max(||q||,eps)*max(||k||,eps)) * temperature, softmax over d
// ---------------------------------------------------------------------------
__global__ void k_softmax(
    const float* __restrict__ dots, const float* __restrict__ sqq,
    const float* __restrict__ sqk, const float* __restrict__ temp,
    float* __restrict__ attn)
{
    int t = threadIdx.x;
    int b = t >> 6, h = (t >> 4) & 3, cq = t & 15;
    float nq = fmaxf(sqrtf(sqq[b*64 + h*16 + cq]), 1e-12f);
    float tp = temp[h];
    float l[16];
    float m = -1e30f;
    #pragma unroll
    for (int d = 0; d < 16; d++){
        float nk = fmaxf(sqrtf(sqk[b*64 + h*16 + d]), 1e-12f);
        float v = dots[((b*4+h)*16 + cq)*16 + d] / (nq*nk) * tp;
        l[d] = v; m = fmaxf(m, v);
    }
    float s = 0.f;
    #pragma unroll
    for (int d = 0; d < 16; d++){ l[d] = __expf(l[d]-m); s += l[d]; }
    float invs = 1.0f / s;
    #pragma unroll
    for (int d = 0; d < 16; d++) attn[((b*4+h)*16 + cq)*16 + d] = l[d]*invs;
}

// ---------------------------------------------------------------------------
// K5: out = attn@v (per-pixel 16x16 matvec per head) -> 1x1 proj -> +x residual
//     -> x1 (to d_out); also emit per-pixel LN2 stats (mu, inv_sigma).
// ---------------------------------------------------------------------------
__global__ __launch_bounds__(256) void k_attnv_proj(
    const float* __restrict__ v, const float* __restrict__ x,
    const float* __restrict__ attn, const float* __restrict__ wproj,
    float* __restrict__ x1out, float* __restrict__ muout, float* __restrict__ invout)
{
    __shared__ float s_attn[1024];
    __shared__ float s_wp[4096];
    int t = threadIdx.x;
    int b = blockIdx.x >> 8;
    int pos = ((blockIdx.x & 255) << 8) + t;
    for (int j = t; j < 4096; j += 256) s_wp[j] = wproj[j];
    for (int j = t; j < 1024; j += 256) s_attn[j] = attn[b*1024 + j];
    __syncthreads();

    size_t base = (size_t)b*64*HW + pos;
    float o[64];
    #pragma unroll
    for (int h = 0; h < 4; h++){
        float vh[16];
        #pragma unroll
        for (int d = 0; d < 16; d++) vh[d] = v[base + (size_t)(h*16+d)*HW];
        #pragma unroll
        for (int r = 0; r < 16; r++){
            float a = 0.f;
            #pragma unroll
            for (int d = 0; d < 16; d++) a += s_attn[((h*16+r)<<4) + d] * vh[d];
            o[h*16 + r] = a;
        }
    }
    float s = 0.f, ss = 0.f;
    for (int c = 0; c < 64; c++){
        float a = x[base + (size_t)c*HW];
        #pragma unroll
        for (int cp = 0; cp < 64; cp++) a += s_wp[c*64 + cp] * o[cp];
        x1out[base + (size_t)c*HW] = a;
        s += a; ss += a*a;
    }
    float mu  = s * (1.0f/64.0f);
    float var = ss * (1.0f/64.0f) - mu*mu;
    muout[(size_t)b*HW + pos]  = mu;
    invout[(size_t)b*HW + pos] = rsqrtf(var + 1e-5f);
}

// ---------------------------------------------------------------------------
// K6: direct 3x3 conv, 64->64 ch, pad 1. Tile 32x8; thread = 4 px x 16 oc.
// IN_LN: input channel values are LN2(x1) recomputed from x1 + per-pixel stats.
// MODE 0: gelu(acc); 1: acc; 2: ln2(aux1)*sigmoid(acc)+aux2; 3: aux1+acc
// ---------------------------------------------------------------------------
template<int IN_LN, int MODE>
__global__ __launch_bounds__(256, 4) void k_conv3x3(
    const float* __restrict__ in, const float* __restrict__ wgt,
    float* dst, const float* aux1, const float* aux2,
    const float* __restrict__ mu, const float* __restrict__ inv,
    const float* __restrict__ lnw, const float* __restrict__ lnb)
{
    __shared__ float s_in[10*35];
    __shared__ float s_w[576];
    __shared__ float s_mu[340], s_inv[340];
    int t  = threadIdx.x;
    int b  = blockIdx.z;
    int x0 = blockIdx.x * 32, y0 = blockIdx.y * 8;
    int qd = t >> 6, g = t & 63;
    int oc0 = qd * 16;
    int ty = g >> 3, tx = (g & 7) << 2;

    if (IN_LN || MODE == 2){
        for (int j = t; j < 340; j += 256){
            int r = j / 34, cc = j - r*34;
            int gy = y0 - 1 + r, gx = x0 - 1 + cc;
            float m = 0.f, iv = 0.f;
            if (gy >= 0 && gy < 256 && gx >= 0 && gx < 256){
                size_t p = (size_t)b*HW + gy*256 + gx;
                m = mu[p]; iv = inv[p];
            }
            s_mu[j] = m; s_inv[j] = iv;
        }
    }

    float acc[16][4];
    #pragma unroll
    for (int i = 0; i < 16; i++){ acc[i][0]=0.f; acc[i][1]=0.f; acc[i][2]=0.f; acc[i][3]=0.f; }

    for (int ic = 0; ic < 64; ic++){
        __syncthreads();
        const float* src = in + (size_t)(b*64+ic)*HW;
        float wln = 0.f, bln = 0.f;
        if (IN_LN){ wln = lnw[ic]; bln = lnb[ic]; }
        for (int j = t; j < 340; j += 256){
            int r = j / 34, cc = j - r*34;
            int gy = y0 - 1 + r, gx = x0 - 1 + cc;
            float val = 0.f;
            if (gy >= 0 && gy < 256 && gx >= 0 && gx < 256){
                float raw = src[gy*256 + gx];
                val = IN_LN ? ((raw - s_mu[j]) * s_inv[j] * wln + bln) : raw;
            }
            s_in[r*35 + cc] = val;
        }
        for (int j = t; j < 576; j += 256){
            int oc = j / 9, kk = j - oc*9;
            s_w[j] = wgt[(size_t)(oc*64 + ic)*9 + kk];
        }
        __syncthreads();

        float n[3][6];
        #pragma unroll
        for (int r = 0; r < 3; r++)
            #pragma unroll
            for (int cc = 0; cc < 6; cc++) n[r][cc] = s_in[(ty+r)*35 + tx+cc];

        #pragma unroll
        for (int oc = 0; oc < 16; oc++){
            const float* wp = &s_w[(oc0+oc)*9];
            float w0=wp[0], w1=wp[1], w2=wp[2], w3=wp[3], w4=wp[4],
                  w5=wp[5], w6=wp[6], w7=wp[7], w8=wp[8];
            #pragma unroll
            for (int px = 0; px < 4; px++){
                acc[oc][px] += w0*n[0][px] + w1*n[0][px+1] + w2*n[0][px+2]
                             + w3*n[1][px] + w4*n[1][px+1] + w5*n[1][px+2]
                             + w6*n[2][px] + w7*n[2][px+1] + w8*n[2][px+2];
            }
        }
    }
    #pragma unroll
    for (int oc = 0; oc < 16; oc++){
        size_t idx = (size_t)(b*64 + oc0 + oc)*HW + (size_t)(y0+ty)*256 + x0 + tx;
        float4 r;
        float* pr = &r.x;
        float lw = 0.f, lb = 0.f;
        if (MODE == 2){ lw = lnw[oc0+oc]; lb = lnb[oc0+oc]; }
        #pragma unroll
        for (int px = 0; px < 4; px++){
            float a = acc[oc][px];
            if (MODE == 0)      a = gelu_exact(a);
            else if (MODE == 2){
                int j = (ty+1)*34 + (tx+px+1);
                float yv = (aux1[idx+px] - s_mu[j]) * s_inv[j] * lw + lb;
                a = yv * sigmoid_(a) + aux2[idx+px];
            }
            else if (MODE == 3) a = aux1[idx+px] + a;
            pr[px] = a;
        }
        *(float4*)(dst + idx) = r;
    }
}

// ---------------------------------------------------------------------------
extern "C" void kernel_launch(void* const* d_in, const int* in_sizes, int n_in,
                              void* d_out, int out_size, void* d_ws, size_t ws_size,
                              hipStream_t stream)
{
    const float* x     = (const float*)d_in[0];
    const float* ref   = (const float*)d_in[1];
    const float* ln1w  = (const float*)d_in[2];
    const float* ln1b  = (const float*)d_in[3];
    const float* ln2w  = (const float*)d_in[4];
    const float* ln2b  = (const float*)d_in[5];
    const float* ln3w  = (const float*)d_in[6];
    const float* ln3b  = (const float*)d_in[7];
    const float* wkv   = (const float*)d_in[8];
    const float* wkvdw = (const float*)d_in[9];
    const float* wq    = (const float*)d_in[10];
    const float* wqdw  = (const float*)d_in[11];
    const float* wproj = (const float*)d_in[12];
    const float* temp  = (const float*)d_in[13];
    const float* wadd1 = (const float*)d_in[14];
    const float* wadd2 = (const float*)d_in[15];
    const float* wmul1 = (const float*)d_in[16];
    const float* wfuse = (const float*)d_in[17];
    float* out = (float*)d_out;

    const size_t S = (size_t)4 * 64 * HW;   // 16,777,216 elements per tensor
    float* ws = (float*)d_ws;
    float* b0   = ws;            // kpre -> v -> z
    float* b1   = ws + S;        // vpre -> t1 -> t2
    float* b2   = ws + 2*S;      // qpre -> k -> x_add
    float* muA  = ws + 3*S;      // per-pixel LN2 mean      (NPOS)
    float* invA = muA + NPOS;    // per-pixel LN2 inv-sigma (NPOS)
    float* dots = invA + NPOS;   // 4096
    float* sqq  = dots + 4096;   // 256
    float* sqk  = sqq + 256;     // 256
    float* attn = sqk + 256;     // 4096
    if (ws_size < (3*S + 2*(size_t)NPOS + 8704) * sizeof(float)) return;

    // LN1/LN3 + 1x1 convs (block 0 zeroes dots/sqq/sqk): kpre->b0, vpre->b1, qpre->b2
    k_ln_1x1<<<1024, 256, 0, stream>>>(x, ref, ln1w, ln1b, ln3w, ln3b, wkv, wq,
                                       b0, b1, b2, dots);
    // depthwise 3x3: q (b2->out), k (b0->b2), v (b1->b0)
    dim3 gdw(8, 32, 256);
    k_dw3x3<<<gdw, 256, 0, stream>>>(b2, wqdw,         out);
    k_dw3x3<<<gdw, 256, 0, stream>>>(b0, wkvdw,        b2);
    k_dw3x3<<<gdw, 256, 0, stream>>>(b1, wkvdw + 64*9, b0);

    k_qk_dots<<<256, 256, 0, stream>>>(out, b2, dots, sqq, sqk);
    k_softmax<<<1, 256, 0, stream>>>(dots, sqq, sqk, temp, attn);

    // attn@v + proj + residual -> x1 (d_out) + LN2 stats
    k_attnv_proj<<<1024, 256, 0, stream>>>(b0, x, attn, wproj, out, muA, invA);

    // SFM: 5 direct 3x3 convs with fused epilogues (y recomputed from x1+stats)
    dim3 gc(8, 32, 4);
    k_conv3x3<1,0><<<gc, 256, 0, stream>>>(out, wadd1, b1, nullptr, nullptr,
                                           muA, invA, ln2w, ln2b);           // t1
    k_conv3x3<0,1><<<gc, 256, 0, stream>>>(b1, wadd2, b2, nullptr, nullptr,
                                           muA, invA, ln2w, ln2b);           // x_add
    k_conv3x3<1,0><<<gc, 256, 0, stream>>>(out, wmul1, b1, nullptr, nullptr,
                                           muA, invA, ln2w, ln2b);           // t2
    k_conv3x3<0,2><<<gc, 256, 0, stream>>>(b1, wmul1, b0, out, b2,
                                           muA, invA, ln2w, ln2b);           // z
    k_conv3x3<0,3><<<gc, 256, 0, stream>>>(b0, wfuse, out, out, nullptr,
                                           muA, invA, ln2w, ln2b);           // final
}

// Round 3
// 2391.808 us; speedup vs baseline: 1.2952x; 1.2952x over previous
//
#include <hip/hip_runtime.h>
#include <math.h>

#define HW 65536
#define NPOS 262144   // B*HW

__device__ __forceinline__ float gelu_exact(float v){
    return 0.5f * v * (1.0f + erff(v * 0.70710678118654752f));
}
__device__ __forceinline__ float sigmoid_(float v){
    return 1.0f / (1.0f + __expf(-v));
}

// ---------------------------------------------------------------------------
// K1: LN1(ref) -> 1x1 w_kv (k_pre,v_pre) ; LN3(x) -> 1x1 w_q (q_pre)
// Block 0 also zeroes the small accumulator region (dots/sqq/sqk).
// ---------------------------------------------------------------------------
__global__ __launch_bounds__(256) void k_ln_1x1(
    const float* __restrict__ x, const float* __restrict__ ref,
    const float* __restrict__ ln1w, const float* __restrict__ ln1b,
    const float* __restrict__ ln3w, const float* __restrict__ ln3b,
    const float* __restrict__ wkv, const float* __restrict__ wq,
    float* __restrict__ kpre, float* __restrict__ vpre, float* __restrict__ qpre,
    float* __restrict__ zbuf)
{
    __shared__ float s_wkv[128*64];
    __shared__ float s_wq[64*64];
    __shared__ float s_l1w[64], s_l1b[64], s_l3w[64], s_l3b[64];
    int t = threadIdx.x;
    if (blockIdx.x == 0){
        for (int j = t; j < 4608; j += 256) zbuf[j] = 0.f;
    }
    for (int j = t; j < 128*64; j += 256) s_wkv[j] = wkv[j];
    for (int j = t; j < 64*64;  j += 256) s_wq[j]  = wq[j];
    if (t < 64){ s_l1w[t]=ln1w[t]; s_l1b[t]=ln1b[t]; s_l3w[t]=ln3w[t]; s_l3b[t]=ln3b[t]; }
    __syncthreads();

    unsigned gid = blockIdx.x * 256u + t;
    unsigned b = gid >> 16, pos = gid & 65535u;
    const size_t base = (size_t)b * 64 * HW + pos;

    float v[64];
    // ---- phase A: ref -> LN1 -> kv 1x1 ----
    float s = 0.f, ss = 0.f;
    #pragma unroll
    for (int c = 0; c < 64; c++){ float r = ref[base + (size_t)c*HW]; v[c] = r; s += r; ss += r*r; }
    float mu  = s * (1.0f/64.0f);
    float var = ss * (1.0f/64.0f) - mu*mu;
    float inv = rsqrtf(var + 1e-5f);
    #pragma unroll
    for (int c = 0; c < 64; c++) v[c] = (v[c]-mu)*inv*s_l1w[c] + s_l1b[c];
    for (int oc = 0; oc < 64; oc++){
        float a = 0.f, a2 = 0.f;
        #pragma unroll
        for (int c = 0; c < 64; c++){
            a  += s_wkv[oc*64 + c]       * v[c];
            a2 += s_wkv[(oc+64)*64 + c]  * v[c];
        }
        kpre[(size_t)(b*64+oc)*HW + pos] = a;
        vpre[(size_t)(b*64+oc)*HW + pos] = a2;
    }
    // ---- phase B: x -> LN3 -> q 1x1 ----
    s = 0.f; ss = 0.f;
    #pragma unroll
    for (int c = 0; c < 64; c++){ float r = x[base + (size_t)c*HW]; v[c] = r; s += r; ss += r*r; }
    mu  = s * (1.0f/64.0f);
    var = ss * (1.0f/64.0f) - mu*mu;
    inv = rsqrtf(var + 1e-5f);
    #pragma unroll
    for (int c = 0; c < 64; c++) v[c] = (v[c]-mu)*inv*s_l3w[c] + s_l3b[c];
    for (int oc = 0; oc < 64; oc++){
        float a = 0.f;
        #pragma unroll
        for (int c = 0; c < 64; c++) a += s_wq[oc*64 + c] * v[c];
        qpre[(size_t)(b*64+oc)*HW + pos] = a;
    }
}

// ---------------------------------------------------------------------------
// K2: depthwise 3x3, pad 1. w9 indexed by [ch*9+k] (caller offsets base ptr).
// ---------------------------------------------------------------------------
__global__ __launch_bounds__(256) void k_dw3x3(
    const float* __restrict__ in, const float* __restrict__ w9,
    float* __restrict__ out)
{
    __shared__ float s_in[10*35];
    int t  = threadIdx.x;
    int b  = blockIdx.z >> 6, ch = blockIdx.z & 63;
    int x0 = blockIdx.x * 32, y0 = blockIdx.y * 8;
    const float* src = in + (size_t)(b*64+ch)*HW;
    for (int j = t; j < 340; j += 256){
        int r = j / 34, cc = j - r*34;
        int gy = y0 - 1 + r, gx = x0 - 1 + cc;
        float val = 0.f;
        if (gy >= 0 && gy < 256 && gx >= 0 && gx < 256) val = src[gy*256 + gx];
        s_in[r*35 + cc] = val;
    }
    float w[9];
    #pragma unroll
    for (int k = 0; k < 9; k++) w[k] = w9[ch*9 + k];
    __syncthreads();
    int ty = t >> 5, tx = t & 31;
    float a = 0.f;
    #pragma unroll
    for (int ky = 0; ky < 3; ky++)
        #pragma unroll
        for (int kx = 0; kx < 3; kx++)
            a += w[ky*3+kx] * s_in[(ty+ky)*35 + tx+kx];
    out[(size_t)(b*64+ch)*HW + (y0+ty)*256 + x0+tx] = a;
}

// ---------------------------------------------------------------------------
// K3: q.kT dots (per head 16x16) + per-channel sum-of-squares, via LDS tiles
// and atomicAdd partial reduction. 256 blocks = 4 batches x 64 pixel chunks.
// ---------------------------------------------------------------------------
__global__ __launch_bounds__(256) void k_qk_dots(
    const float* __restrict__ q, const float* __restrict__ k,
    float* __restrict__ dots, float* __restrict__ sqq, float* __restrict__ sqk)
{
    __shared__ float qs[64*65];
    __shared__ float ks[64*65];
    int t = threadIdx.x;
    int b = blockIdx.x >> 6;
    int p0 = (blockIdx.x & 63) * 1024;
    int plane = t & 63, cb = t >> 6;
    int h = t >> 6, cq = (t >> 2) & 15, ck0 = (t & 3) << 2;
    int cQ = h*16 + cq, cK = h*16 + ck0;
    float acc0=0,acc1=0,acc2=0,acc3=0, sacc=0;

    for (int sblk = 0; sblk < 16; sblk++){
        __syncthreads();
        int pbase = p0 + sblk*64;
        for (int i = 0; i < 16; i++){
            int c = cb + 4*i;
            qs[plane*65 + c] = q[(size_t)(b*64+c)*HW + pbase + plane];
            ks[plane*65 + c] = k[(size_t)(b*64+c)*HW + pbase + plane];
        }
        __syncthreads();
        for (int p = 0; p < 64; p++){
            float qv = qs[p*65 + cQ];
            acc0 += qv * ks[p*65 + cK + 0];
            acc1 += qv * ks[p*65 + cK + 1];
            acc2 += qv * ks[p*65 + cK + 2];
            acc3 += qv * ks[p*65 + cK + 3];
        }
        if (t < 64){
            for (int p = 0; p < 64; p++){ float vv = qs[p*65 + t]; sacc += vv*vv; }
        } else if (t < 128){
            int c = t - 64;
            for (int p = 0; p < 64; p++){ float vv = ks[p*65 + c]; sacc += vv*vv; }
        }
    }
    int dbase = ((b*4 + h)*16 + cq)*16 + ck0;
    atomicAdd(&dots[dbase+0], acc0);
    atomicAdd(&dots[dbase+1], acc1);
    atomicAdd(&dots[dbase+2], acc2);
    atomicAdd(&dots[dbase+3], acc3);
    if (t < 64)       atomicAdd(&sqq[b*64 + t], sacc);
    else if (t < 128) atomicAdd(&sqk[b*64 + t - 64], sacc);
}

// ---------------------------------------------------------------------------
// K4: scale by 1/(max(||q||,eps)*max(||k||,eps)) * temperature, softmax over d
// ---------------------------------------------------------------------------
__global__ void k_softmax(
    const float* __restrict__ dots, const float* __restrict__ sqq,
    const float* __restrict__ sqk, const float* __restrict__ temp,
    float* __restrict__ attn)
{
    int t = threadIdx.x;
    int b = t >> 6, h = (t >> 4) & 3, cq = t & 15;
    float nq = fmaxf(sqrtf(sqq[b*64 + h*16 + cq]), 1e-12f);
    float tp = temp[h];
    float l[16];
    float m = -1e30f;
    #pragma unroll
    for (int d = 0; d < 16; d++){
        float nk = fmaxf(sqrtf(sqk[b*64 + h*16 + d]), 1e-12f);
        float v = dots[((b*4+h)*16 + cq)*16 + d] / (nq*nk) * tp;
        l[d] = v; m = fmaxf(m, v);
    }
    float s = 0.f;
    #pragma unroll
    for (int d = 0; d < 16; d++){ l[d] = __expf(l[d]-m); s += l[d]; }
    float invs = 1.0f / s;
    #pragma unroll
    for (int d = 0; d < 16; d++) attn[((b*4+h)*16 + cq)*16 + d] = l[d]*invs;
}

// ---------------------------------------------------------------------------
// K5: out = attn@v (per-pixel 16x16 matvec per head) -> 1x1 proj -> +x residual
//     -> x1 (to d_out); also emit per-pixel LN2 stats (mu, inv_sigma).
// ---------------------------------------------------------------------------
__global__ __launch_bounds__(256) void k_attnv_proj(
    const float* __restrict__ v, const float* __restrict__ x,
    const float* __restrict__ attn, const float* __restrict__ wproj,
    float* __restrict__ x1out, float* __restrict__ muout, float* __restrict__ invout)
{
    __shared__ float s_attn[1024];
    __shared__ float s_wp[4096];
    int t = threadIdx.x;
    int b = blockIdx.x >> 8;
    int pos = ((blockIdx.x & 255) << 8) + t;
    for (int j = t; j < 4096; j += 256) s_wp[j] = wproj[j];
    for (int j = t; j < 1024; j += 256) s_attn[j] = attn[b*1024 + j];
    __syncthreads();

    size_t base = (size_t)b*64*HW + pos;
    float o[64];
    #pragma unroll
    for (int h = 0; h < 4; h++){
        float vh[16];
        #pragma unroll
        for (int d = 0; d < 16; d++) vh[d] = v[base + (size_t)(h*16+d)*HW];
        #pragma unroll
        for (int r = 0; r < 16; r++){
            float a = 0.f;
            #pragma unroll
            for (int d = 0; d < 16; d++) a += s_attn[((h*16+r)<<4) + d] * vh[d];
            o[h*16 + r] = a;
        }
    }
    float s = 0.f, ss = 0.f;
    for (int c = 0; c < 64; c++){
        float a = x[base + (size_t)c*HW];
        #pragma unroll
        for (int cp = 0; cp < 64; cp++) a += s_wp[c*64 + cp] * o[cp];
        x1out[base + (size_t)c*HW] = a;
        s += a; ss += a*a;
    }
    float mu  = s * (1.0f/64.0f);
    float var = ss * (1.0f/64.0f) - mu*mu;
    muout[(size_t)b*HW + pos]  = mu;
    invout[(size_t)b*HW + pos] = rsqrtf(var + 1e-5f);
}

// ---------------------------------------------------------------------------
// K6: direct 3x3 conv, 64->64 ch, pad 1. Tile 32x8; thread = 4 px x 16 oc.
// IN_LN: input channel values are LN2(x1) recomputed from x1 + per-pixel stats.
// MODE 0: gelu(acc); 1: acc; 2: ln2(aux1)*sigmoid(acc)+aux2; 3: aux1+acc
// launch_bounds(256,2): VGPR cap 256 — acc[16][4] MUST stay in registers.
// (256,4) capped at 128 and the compiler spilled to scratch: VGPR_Count=64,
// WRITE_SIZE 2.07 GB/dispatch vs 64 MB ideal, VALUBusy 32%. [round-2 rocprof]
// ---------------------------------------------------------------------------
template<int IN_LN, int MODE>
__global__ __launch_bounds__(256, 2) void k_conv3x3(
    const float* __restrict__ in, const float* __restrict__ wgt,
    float* dst, const float* aux1, const float* aux2,
    const float* __restrict__ mu, const float* __restrict__ inv,
    const float* __restrict__ lnw, const float* __restrict__ lnb)
{
    __shared__ float s_in[10*35];
    __shared__ float s_w[576];
    __shared__ float s_mu[340], s_inv[340];
    int t  = threadIdx.x;
    int b  = blockIdx.z;
    int x0 = blockIdx.x * 32, y0 = blockIdx.y * 8;
    int qd = t >> 6, g = t & 63;
    int oc0 = qd * 16;
    int ty = g >> 3, tx = (g & 7) << 2;

    if (IN_LN || MODE == 2){
        for (int j = t; j < 340; j += 256){
            int r = j / 34, cc = j - r*34;
            int gy = y0 - 1 + r, gx = x0 - 1 + cc;
            float m = 0.f, iv = 0.f;
            if (gy >= 0 && gy < 256 && gx >= 0 && gx < 256){
                size_t p = (size_t)b*HW + gy*256 + gx;
                m = mu[p]; iv = inv[p];
            }
            s_mu[j] = m; s_inv[j] = iv;
        }
    }

    float acc[16][4];
    #pragma unroll
    for (int i = 0; i < 16; i++){ acc[i][0]=0.f; acc[i][1]=0.f; acc[i][2]=0.f; acc[i][3]=0.f; }

    for (int ic = 0; ic < 64; ic++){
        __syncthreads();
        const float* src = in + (size_t)(b*64+ic)*HW;
        float wln = 0.f, bln = 0.f;
        if (IN_LN){ wln = lnw[ic]; bln = lnb[ic]; }
        for (int j = t; j < 340; j += 256){
            int r = j / 34, cc = j - r*34;
            int gy = y0 - 1 + r, gx = x0 - 1 + cc;
            float val = 0.f;
            if (gy >= 0 && gy < 256 && gx >= 0 && gx < 256){
                float raw = src[gy*256 + gx];
                val = IN_LN ? ((raw - s_mu[j]) * s_inv[j] * wln + bln) : raw;
            }
            s_in[r*35 + cc] = val;
        }
        for (int j = t; j < 576; j += 256){
            int oc = j / 9, kk = j - oc*9;
            s_w[j] = wgt[(size_t)(oc*64 + ic)*9 + kk];
        }
        __syncthreads();

        float n[3][6];
        #pragma unroll
        for (int r = 0; r < 3; r++)
            #pragma unroll
            for (int cc = 0; cc < 6; cc++) n[r][cc] = s_in[(ty+r)*35 + tx+cc];

        #pragma unroll
        for (int oc = 0; oc < 16; oc++){
            const float* wp = &s_w[(oc0+oc)*9];
            float w0=wp[0], w1=wp[1], w2=wp[2], w3=wp[3], w4=wp[4],
                  w5=wp[5], w6=wp[6], w7=wp[7], w8=wp[8];
            #pragma unroll
            for (int px = 0; px < 4; px++){
                acc[oc][px] += w0*n[0][px] + w1*n[0][px+1] + w2*n[0][px+2]
                             + w3*n[1][px] + w4*n[1][px+1] + w5*n[1][px+2]
                             + w6*n[2][px] + w7*n[2][px+1] + w8*n[2][px+2];
            }
        }
    }
    #pragma unroll
    for (int oc = 0; oc < 16; oc++){
        size_t idx = (size_t)(b*64 + oc0 + oc)*HW + (size_t)(y0+ty)*256 + x0 + tx;
        float4 r;
        float* pr = &r.x;
        float lw = 0.f, lb = 0.f;
        if (MODE == 2){ lw = lnw[oc0+oc]; lb = lnb[oc0+oc]; }
        #pragma unroll
        for (int px = 0; px < 4; px++){
            float a = acc[oc][px];
            if (MODE == 0)      a = gelu_exact(a);
            else if (MODE == 2){
                int j = (ty+1)*34 + (tx+px+1);
                float yv = (aux1[idx+px] - s_mu[j]) * s_inv[j] * lw + lb;
                a = yv * sigmoid_(a) + aux2[idx+px];
            }
            else if (MODE == 3) a = aux1[idx+px] + a;
            pr[px] = a;
        }
        *(float4*)(dst + idx) = r;
    }
}

// ---------------------------------------------------------------------------
extern "C" void kernel_launch(void* const* d_in, const int* in_sizes, int n_in,
                              void* d_out, int out_size, void* d_ws, size_t ws_size,
                              hipStream_t stream)
{
    const float* x     = (const float*)d_in[0];
    const float* ref   = (const float*)d_in[1];
    const float* ln1w  = (const float*)d_in[2];
    const float* ln1b  = (const float*)d_in[3];
    const float* ln2w  = (const float*)d_in[4];
    const float* ln2b  = (const float*)d_in[5];
    const float* ln3w  = (const float*)d_in[6];
    const float* ln3b  = (const float*)d_in[7];
    const float* wkv   = (const float*)d_in[8];
    const float* wkvdw = (const float*)d_in[9];
    const float* wq    = (const float*)d_in[10];
    const float* wqdw  = (const float*)d_in[11];
    const float* wproj = (const float*)d_in[12];
    const float* temp  = (const float*)d_in[13];
    const float* wadd1 = (const float*)d_in[14];
    const float* wadd2 = (const float*)d_in[15];
    const float* wmul1 = (const float*)d_in[16];
    const float* wfuse = (const float*)d_in[17];
    float* out = (float*)d_out;

    const size_t S = (size_t)4 * 64 * HW;   // 16,777,216 elements per tensor
    float* ws = (float*)d_ws;
    float* b0   = ws;            // kpre -> v -> z
    float* b1   = ws + S;        // vpre -> t1 -> t2
    float* b2   = ws + 2*S;      // qpre -> k -> x_add
    float* muA  = ws + 3*S;      // per-pixel LN2 mean      (NPOS)
    float* invA = muA + NPOS;    // per-pixel LN2 inv-sigma (NPOS)
    float* dots = invA + NPOS;   // 4096
    float* sqq  = dots + 4096;   // 256
    float* sqk  = sqq + 256;     // 256
    float* attn = sqk + 256;     // 4096
    if (ws_size < (3*S + 2*(size_t)NPOS + 8704) * sizeof(float)) return;

    // LN1/LN3 + 1x1 convs (block 0 zeroes dots/sqq/sqk): kpre->b0, vpre->b1, qpre->b2
    k_ln_1x1<<<1024, 256, 0, stream>>>(x, ref, ln1w, ln1b, ln3w, ln3b, wkv, wq,
                                       b0, b1, b2, dots);
    // depthwise 3x3: q (b2->out), k (b0->b2), v (b1->b0)
    dim3 gdw(8, 32, 256);
    k_dw3x3<<<gdw, 256, 0, stream>>>(b2, wqdw,         out);
    k_dw3x3<<<gdw, 256, 0, stream>>>(b0, wkvdw,        b2);
    k_dw3x3<<<gdw, 256, 0, stream>>>(b1, wkvdw + 64*9, b0);

    k_qk_dots<<<256, 256, 0, stream>>>(out, b2, dots, sqq, sqk);
    k_softmax<<<1, 256, 0, stream>>>(dots, sqq, sqk, temp, attn);

    // attn@v + proj + residual -> x1 (d_out) + LN2 stats
    k_attnv_proj<<<1024, 256, 0, stream>>>(b0, x, attn, wproj, out, muA, invA);

    // SFM: 5 direct 3x3 convs with fused epilogues (y recomputed from x1+stats)
    dim3 gc(8, 32, 4);
    k_conv3x3<1,0><<<gc, 256, 0, stream>>>(out, wadd1, b1, nullptr, nullptr,
                                           muA, invA, ln2w, ln2b);           // t1
    k_conv3x3<0,1><<<gc, 256, 0, stream>>>(b1, wadd2, b2, nullptr, nullptr,
                                           muA, invA, ln2w, ln2b);           // x_add
    k_conv3x3<1,0><<<gc, 256, 0, stream>>>(out, wmul1, b1, nullptr, nullptr,
                                           muA, invA, ln2w, ln2b);           // t2
    k_conv3x3<0,2><<<gc, 256, 0, stream>>>(b1, wmul1, b0, out, b2,
                                           muA, invA, ln2w, ln2b);           // z
    k_conv3x3<0,3><<<gc, 256, 0, stream>>>(b0, wfuse, out, out, nullptr,
                                           muA, invA, ln2w, ln2b);           // final
}

// Round 4
// 992.072 us; speedup vs baseline: 3.1227x; 2.4109x over previous
//
#include <hip/hip_runtime.h>
#include <math.h>

#define HW 65536
#define NPOS 262144   // B*HW

typedef __attribute__((ext_vector_type(8))) short short8;
typedef __attribute__((ext_vector_type(4))) float float4v;

__device__ __forceinline__ float gelu_exact(float v){
    return 0.5f * v * (1.0f + erff(v * 0.70710678118654752f));
}
__device__ __forceinline__ float sigmoid_(float v){
    return 1.0f / (1.0f + __expf(-v));
}
__device__ __forceinline__ unsigned short f2bf(float f){
    unsigned u = __builtin_bit_cast(unsigned, f);
    unsigned r = (u + 0x7fffu + ((u >> 16) & 1u)) >> 16;
    return (unsigned short)r;
}
__device__ __forceinline__ float bf2f(unsigned short h){
    unsigned u = ((unsigned)h) << 16;
    return __builtin_bit_cast(float, u);
}

// ---------------------------------------------------------------------------
// K0: transform the 4 SFM 3x3 weight tensors [oc][ic][9] fp32 -> [w][tap][oc][ic] bf16
// ---------------------------------------------------------------------------
__global__ __launch_bounds__(256) void k_wprep(
    const float* __restrict__ w0, const float* __restrict__ w1,
    const float* __restrict__ w2, const float* __restrict__ w3,
    unsigned short* __restrict__ dst)
{
    int gid = blockIdx.x * 256 + threadIdx.x;   // < 4*36864
    int w = gid / 36864;
    int rem = gid - w * 36864;
    int t = rem >> 12;            // tap
    int oi = rem & 4095;
    int oc = oi >> 6, ic = oi & 63;
    const float* src = (w == 0) ? w0 : (w == 1) ? w1 : (w == 2) ? w2 : w3;
    dst[gid] = f2bf(src[oc*576 + ic*9 + t]);
}

// ---------------------------------------------------------------------------
// K1: LN1(ref) -> 1x1 w_kv (k_pre,v_pre) ; LN3(x) -> 1x1 w_q (q_pre)
// Block 0 also zeroes the small accumulator region (dots/sqq/sqk).
// ---------------------------------------------------------------------------
__global__ __launch_bounds__(256) void k_ln_1x1(
    const float* __restrict__ x, const float* __restrict__ ref,
    const float* __restrict__ ln1w, const float* __restrict__ ln1b,
    const float* __restrict__ ln3w, const float* __restrict__ ln3b,
    const float* __restrict__ wkv, const float* __restrict__ wq,
    float* __restrict__ kpre, float* __restrict__ vpre, float* __restrict__ qpre,
    float* __restrict__ zbuf)
{
    __shared__ float s_wkv[128*64];
    __shared__ float s_wq[64*64];
    __shared__ float s_l1w[64], s_l1b[64], s_l3w[64], s_l3b[64];
    int t = threadIdx.x;
    if (blockIdx.x == 0){
        for (int j = t; j < 4608; j += 256) zbuf[j] = 0.f;
    }
    for (int j = t; j < 128*64; j += 256) s_wkv[j] = wkv[j];
    for (int j = t; j < 64*64;  j += 256) s_wq[j]  = wq[j];
    if (t < 64){ s_l1w[t]=ln1w[t]; s_l1b[t]=ln1b[t]; s_l3w[t]=ln3w[t]; s_l3b[t]=ln3b[t]; }
    __syncthreads();

    unsigned gid = blockIdx.x * 256u + t;
    unsigned b = gid >> 16, pos = gid & 65535u;
    const size_t base = (size_t)b * 64 * HW + pos;

    float v[64];
    float s = 0.f, ss = 0.f;
    #pragma unroll
    for (int c = 0; c < 64; c++){ float r = ref[base + (size_t)c*HW]; v[c] = r; s += r; ss += r*r; }
    float mu  = s * (1.0f/64.0f);
    float var = ss * (1.0f/64.0f) - mu*mu;
    float inv = rsqrtf(var + 1e-5f);
    #pragma unroll
    for (int c = 0; c < 64; c++) v[c] = (v[c]-mu)*inv*s_l1w[c] + s_l1b[c];
    for (int oc = 0; oc < 64; oc++){
        float a = 0.f, a2 = 0.f;
        #pragma unroll
        for (int c = 0; c < 64; c++){
            a  += s_wkv[oc*64 + c]       * v[c];
            a2 += s_wkv[(oc+64)*64 + c]  * v[c];
        }
        kpre[(size_t)(b*64+oc)*HW + pos] = a;
        vpre[(size_t)(b*64+oc)*HW + pos] = a2;
    }
    s = 0.f; ss = 0.f;
    #pragma unroll
    for (int c = 0; c < 64; c++){ float r = x[base + (size_t)c*HW]; v[c] = r; s += r; ss += r*r; }
    mu  = s * (1.0f/64.0f);
    var = ss * (1.0f/64.0f) - mu*mu;
    inv = rsqrtf(var + 1e-5f);
    #pragma unroll
    for (int c = 0; c < 64; c++) v[c] = (v[c]-mu)*inv*s_l3w[c] + s_l3b[c];
    for (int oc = 0; oc < 64; oc++){
        float a = 0.f;
        #pragma unroll
        for (int c = 0; c < 64; c++) a += s_wq[oc*64 + c] * v[c];
        qpre[(size_t)(b*64+oc)*HW + pos] = a;
    }
}

// ---------------------------------------------------------------------------
// K2: depthwise 3x3, pad 1 (fp32 NCHW).
// ---------------------------------------------------------------------------
__global__ __launch_bounds__(256) void k_dw3x3(
    const float* __restrict__ in, const float* __restrict__ w9,
    float* __restrict__ out)
{
    __shared__ float s_in[10*35];
    int t  = threadIdx.x;
    int b  = blockIdx.z >> 6, ch = blockIdx.z & 63;
    int x0 = blockIdx.x * 32, y0 = blockIdx.y * 8;
    const float* src = in + (size_t)(b*64+ch)*HW;
    for (int j = t; j < 340; j += 256){
        int r = j / 34, cc = j - r*34;
        int gy = y0 - 1 + r, gx = x0 - 1 + cc;
        float val = 0.f;
        if (gy >= 0 && gy < 256 && gx >= 0 && gx < 256) val = src[gy*256 + gx];
        s_in[r*35 + cc] = val;
    }
    float w[9];
    #pragma unroll
    for (int k = 0; k < 9; k++) w[k] = w9[ch*9 + k];
    __syncthreads();
    int ty = t >> 5, tx = t & 31;
    float a = 0.f;
    #pragma unroll
    for (int ky = 0; ky < 3; ky++)
        #pragma unroll
        for (int kx = 0; kx < 3; kx++)
            a += w[ky*3+kx] * s_in[(ty+ky)*35 + tx+kx];
    out[(size_t)(b*64+ch)*HW + (y0+ty)*256 + x0+tx] = a;
}

// ---------------------------------------------------------------------------
// K3: q.kT dots (per head 16x16) + per-channel sum-of-squares.
// ---------------------------------------------------------------------------
__global__ __launch_bounds__(256) void k_qk_dots(
    const float* __restrict__ q, const float* __restrict__ k,
    float* __restrict__ dots, float* __restrict__ sqq, float* __restrict__ sqk)
{
    __shared__ float qs[64*65];
    __shared__ float ks[64*65];
    int t = threadIdx.x;
    int b = blockIdx.x >> 6;
    int p0 = (blockIdx.x & 63) * 1024;
    int plane = t & 63, cb = t >> 6;
    int h = t >> 6, cq = (t >> 2) & 15, ck0 = (t & 3) << 2;
    int cQ = h*16 + cq, cK = h*16 + ck0;
    float acc0=0,acc1=0,acc2=0,acc3=0, sacc=0;

    for (int sblk = 0; sblk < 16; sblk++){
        __syncthreads();
        int pbase = p0 + sblk*64;
        for (int i = 0; i < 16; i++){
            int c = cb + 4*i;
            qs[plane*65 + c] = q[(size_t)(b*64+c)*HW + pbase + plane];
            ks[plane*65 + c] = k[(size_t)(b*64+c)*HW + pbase + plane];
        }
        __syncthreads();
        for (int p = 0; p < 64; p++){
            float qv = qs[p*65 + cQ];
            acc0 += qv * ks[p*65 + cK + 0];
            acc1 += qv * ks[p*65 + cK + 1];
            acc2 += qv * ks[p*65 + cK + 2];
            acc3 += qv * ks[p*65 + cK + 3];
        }
        if (t < 64){
            for (int p = 0; p < 64; p++){ float vv = qs[p*65 + t]; sacc += vv*vv; }
        } else if (t < 128){
            int c = t - 64;
            for (int p = 0; p < 64; p++){ float vv = ks[p*65 + c]; sacc += vv*vv; }
        }
    }
    int dbase = ((b*4 + h)*16 + cq)*16 + ck0;
    atomicAdd(&dots[dbase+0], acc0);
    atomicAdd(&dots[dbase+1], acc1);
    atomicAdd(&dots[dbase+2], acc2);
    atomicAdd(&dots[dbase+3], acc3);
    if (t < 64)       atomicAdd(&sqq[b*64 + t], sacc);
    else if (t < 128) atomicAdd(&sqk[b*64 + t - 64], sacc);
}

// ---------------------------------------------------------------------------
// K4: normalize + temperature + softmax over d
// ---------------------------------------------------------------------------
__global__ void k_softmax(
    const float* __restrict__ dots, const float* __restrict__ sqq,
    const float* __restrict__ sqk, const float* __restrict__ temp,
    float* __restrict__ attn)
{
    int t = threadIdx.x;
    int b = t >> 6, h = (t >> 4) & 3, cq = t & 15;
    float nq = fmaxf(sqrtf(sqq[b*64 + h*16 + cq]), 1e-12f);
    float tp = temp[h];
    float l[16];
    float m = -1e30f;
    #pragma unroll
    for (int d = 0; d < 16; d++){
        float nk = fmaxf(sqrtf(sqk[b*64 + h*16 + d]), 1e-12f);
        float v = dots[((b*4+h)*16 + cq)*16 + d] / (nq*nk) * tp;
        l[d] = v; m = fmaxf(m, v);
    }
    float s = 0.f;
    #pragma unroll
    for (int d = 0; d < 16; d++){ l[d] = __expf(l[d]-m); s += l[d]; }
    float invs = 1.0f / s;
    #pragma unroll
    for (int d = 0; d < 16; d++) attn[((b*4+h)*16 + cq)*16 + d] = l[d]*invs;
}

// ---------------------------------------------------------------------------
// K5: attn@v -> 1x1 proj -> +x residual -> x1; emit x1 and y=LN2(x1) as
// bf16 NHWC [b][y][x][c] for the MFMA SFM convs.
// ---------------------------------------------------------------------------
__global__ __launch_bounds__(256, 2) void k_attnv_proj(
    const float* __restrict__ v, const float* __restrict__ x,
    const float* __restrict__ attn, const float* __restrict__ wproj,
    const float* __restrict__ ln2w, const float* __restrict__ ln2b,
    unsigned short* __restrict__ x1_bf, unsigned short* __restrict__ y_bf)
{
    __shared__ float s_attn[1024];
    __shared__ float s_wp[4096];
    __shared__ float s_lw[64], s_lb[64];
    int t = threadIdx.x;
    int b = blockIdx.x >> 8;
    int pos = ((blockIdx.x & 255) << 8) + t;
    for (int j = t; j < 4096; j += 256) s_wp[j] = wproj[j];
    for (int j = t; j < 1024; j += 256) s_attn[j] = attn[b*1024 + j];
    if (t < 64){ s_lw[t] = ln2w[t]; s_lb[t] = ln2b[t]; }
    __syncthreads();

    size_t base = (size_t)b*64*HW + pos;
    float o[64];
    #pragma unroll
    for (int h = 0; h < 4; h++){
        float vh[16];
        #pragma unroll
        for (int d = 0; d < 16; d++) vh[d] = v[base + (size_t)(h*16+d)*HW];
        #pragma unroll
        for (int r = 0; r < 16; r++){
            float a = 0.f;
            #pragma unroll
            for (int d = 0; d < 16; d++) a += s_attn[((h*16+r)<<4) + d] * vh[d];
            o[h*16 + r] = a;
        }
    }
    float a[64];
    float s = 0.f, ss = 0.f;
    for (int c = 0; c < 64; c++){
        float av = x[base + (size_t)c*HW];
        #pragma unroll
        for (int cp = 0; cp < 64; cp++) av += s_wp[c*64 + cp] * o[cp];
        a[c] = av; s += av; ss += av*av;
    }
    float mu  = s * (1.0f/64.0f);
    float var = ss * (1.0f/64.0f) - mu*mu;
    float inv = rsqrtf(var + 1e-5f);

    size_t nb = ((size_t)b*HW + pos) * 64;
    for (int c0 = 0; c0 < 64; c0 += 8){
        unsigned short xv[8], yv[8];
        #pragma unroll
        for (int i = 0; i < 8; i++){
            float f = a[c0+i];
            xv[i] = f2bf(f);
            yv[i] = f2bf((f - mu) * inv * s_lw[c0+i] + s_lb[c0+i]);
        }
        *(short8*)(x1_bf + nb + c0) = *(short8*)xv;
        *(short8*)(y_bf  + nb + c0) = *(short8*)yv;
    }
}

// ---------------------------------------------------------------------------
// K6: 3x3 conv 64->64 as 9 shifted MFMA GEMM taps (bf16 in, fp32 acc).
// Input NHWC bf16, weights [tap][oc][ic] bf16.
// Tile: 2 rows x 128 px x 64 oc per block (4 waves, each 64 oc x 64 px).
// LDS: X [4 rows][130 px][ic pad 40] per 32-ic chunk + W tap double-buffer.
// MODE 0: gelu->bf16 | 1: ->bf16 | 2: y*sigmoid(acc)+xadd->bf16 | 3: x1+acc->fp32 NCHW
// ---------------------------------------------------------------------------
template<int MODE>
__global__ __launch_bounds__(256, 3) void k_conv3x3_mfma(
    const unsigned short* __restrict__ in,
    const unsigned short* __restrict__ wt,
    unsigned short* __restrict__ dst,
    const unsigned short* __restrict__ auxA,
    const unsigned short* __restrict__ auxB,
    float* __restrict__ outf)
{
    __shared__ unsigned short Xs[4*130*40];   // 41600 B
    __shared__ unsigned short Ws[2][64*40];   // 10240 B
    int tid  = threadIdx.x;
    int b    = blockIdx.z;
    int y0   = blockIdx.y * 2;
    int x0   = blockIdx.x * 128;
    int wave = tid >> 6, lane = tid & 63;
    int q = lane >> 4, l = lane & 15;
    int r = wave >> 1;               // out row within tile (0..1)
    int pb = (wave & 1) * 64;        // px base within tile

    float4v acc[4][4];
    #pragma unroll
    for (int m = 0; m < 4; m++)
        #pragma unroll
        for (int n = 0; n < 4; n++) acc[m][n] = (float4v){0.f,0.f,0.f,0.f};

    for (int c = 0; c < 2; ++c){
        __syncthreads();
        // stage X chunk: 4 rows x 130 px x 32 ic (as 16B pieces)
        for (int j = tid; j < 2080; j += 256){
            int row = j / 520;
            int rem = j - row*520;
            int px  = rem >> 2;
            int part= rem & 3;
            int gy = y0 - 1 + row, gx = x0 - 1 + px;
            short8 v = (short8)0;
            if (gy >= 0 && gy < 256 && gx >= 0 && gx < 256){
                v = *(const short8*)(in + (((size_t)b*HW + gy*256 + gx) * 64) + c*32 + part*8);
            }
            *(short8*)(&Xs[(row*130 + px)*40 + part*8]) = v;
        }
        // stage W tap 0
        {
            int oc = tid >> 2, part = tid & 3;
            *(short8*)(&Ws[0][oc*40 + part*8]) =
                *(const short8*)(wt + ((size_t)(0*64 + oc))*64 + c*32 + part*8);
        }
        for (int t = 0; t < 9; ++t){
            __syncthreads();
            if (t < 8){
                int oc = tid >> 2, part = tid & 3;
                *(short8*)(&Ws[(t+1)&1][oc*40 + part*8]) =
                    *(const short8*)(wt + ((size_t)((t+1)*64 + oc))*64 + c*32 + part*8);
            }
            int ky = t / 3, kx = t - ky*3;
            const unsigned short* wb = &Ws[t & 1][0];
            short8 afr[4];
            #pragma unroll
            for (int m = 0; m < 4; m++)
                afr[m] = *(const short8*)(wb + (m*16 + l)*40 + q*8);
            #pragma unroll
            for (int n = 0; n < 4; n++){
                int px = pb + n*16 + l;
                short8 bfr = *(const short8*)(&Xs[((r+ky)*130 + px + kx)*40 + q*8]);
                #pragma unroll
                for (int m = 0; m < 4; m++)
                    acc[m][n] = __builtin_amdgcn_mfma_f32_16x16x32_bf16(
                        afr[m], bfr, acc[m][n], 0, 0, 0);
            }
        }
    }

    // epilogue: oc = m*16 + q*4 + rr ; px = pb + n*16 + l ; gy = y0 + r
    int gy = y0 + r;
    #pragma unroll
    for (int n = 0; n < 4; n++){
        int gx = x0 + pb + n*16 + l;
        size_t pixbase = ((size_t)b*HW + gy*256 + gx) * 64;
        #pragma unroll
        for (int m = 0; m < 4; m++){
            int ocb = m*16 + q*4;
            float4v av = acc[m][n];
            if (MODE == 0 || MODE == 1){
                unsigned short pk[4];
                #pragma unroll
                for (int i = 0; i < 4; i++){
                    float f = (MODE == 0) ? gelu_exact(av[i]) : av[i];
                    pk[i] = f2bf(f);
                }
                *(unsigned long long*)(dst + pixbase + ocb) = *(unsigned long long*)pk;
            } else if (MODE == 2){
                unsigned long long yu = *(const unsigned long long*)(auxA + pixbase + ocb);
                unsigned long long xu = *(const unsigned long long*)(auxB + pixbase + ocb);
                const unsigned short* y4 = (const unsigned short*)&yu;
                const unsigned short* xa4 = (const unsigned short*)&xu;
                unsigned short pk[4];
                #pragma unroll
                for (int i = 0; i < 4; i++){
                    float z = bf2f(y4[i]) * sigmoid_(av[i]) + bf2f(xa4[i]);
                    pk[i] = f2bf(z);
                }
                *(unsigned long long*)(dst + pixbase + ocb) = *(unsigned long long*)pk;
            } else {  // MODE 3: final fp32 NCHW out = x1 + acc
                unsigned long long xu = *(const unsigned long long*)(auxA + pixbase + ocb);
                const unsigned short* x14 = (const unsigned short*)&xu;
                #pragma unroll
                for (int i = 0; i < 4; i++){
                    outf[((size_t)(b*64 + ocb + i))*HW + gy*256 + gx] = bf2f(x14[i]) + av[i];
                }
            }
        }
    }
}

// ---------------------------------------------------------------------------
extern "C" void kernel_launch(void* const* d_in, const int* in_sizes, int n_in,
                              void* d_out, int out_size, void* d_ws, size_t ws_size,
                              hipStream_t stream)
{
    const float* x     = (const float*)d_in[0];
    const float* ref   = (const float*)d_in[1];
    const float* ln1w  = (const float*)d_in[2];
    const float* ln1b  = (const float*)d_in[3];
    const float* ln2w  = (const float*)d_in[4];
    const float* ln2b  = (const float*)d_in[5];
    const float* ln3w  = (const float*)d_in[6];
    const float* ln3b  = (const float*)d_in[7];
    const float* wkv   = (const float*)d_in[8];
    const float* wkvdw = (const float*)d_in[9];
    const float* wq    = (const float*)d_in[10];
    const float* wqdw  = (const float*)d_in[11];
    const float* wproj = (const float*)d_in[12];
    const float* temp  = (const float*)d_in[13];
    const float* wadd1 = (const float*)d_in[14];
    const float* wadd2 = (const float*)d_in[15];
    const float* wmul1 = (const float*)d_in[16];
    const float* wfuse = (const float*)d_in[17];
    float* out = (float*)d_out;

    const size_t S = (size_t)4 * 64 * HW;   // 16,777,216 elements per tensor
    float* ws = (float*)d_ws;
    float* b0   = ws;            // kpre -> v ; then z_bf (bf16)
    float* b1   = ws + S;        // vpre ; then y_bf | x1_bf (bf16 halves)
    float* b2   = ws + 2*S;      // qpre -> k ; then t_bf | xadd_bf (bf16 halves)
    float* dots = ws + 3*S;      // 4096
    float* sqq  = dots + 4096;   // 256
    float* sqk  = sqq + 256;     // 256
    float* attn = sqk + 256;     // 4096
    unsigned short* Wt = (unsigned short*)(attn + 4096);  // 4*36864 bf16
    if (ws_size < 3*S*4 + 8704*4 + 4*36864*2) return;

    unsigned short* y_bf    = (unsigned short*)b1;
    unsigned short* x1_bf   = (unsigned short*)b1 + S;
    unsigned short* t_bf    = (unsigned short*)b2;
    unsigned short* xadd_bf = (unsigned short*)b2 + S;
    unsigned short* z_bf    = (unsigned short*)b0;

    // weight prep (independent)
    k_wprep<<<576, 256, 0, stream>>>(wadd1, wadd2, wmul1, wfuse, Wt);

    // LN1/LN3 + 1x1 convs: kpre->b0, vpre->b1, qpre->b2 (block 0 zeroes dots)
    k_ln_1x1<<<1024, 256, 0, stream>>>(x, ref, ln1w, ln1b, ln3w, ln3b, wkv, wq,
                                       b0, b1, b2, dots);
    // depthwise 3x3: q (b2->out), k (b0->b2), v (b1->b0)
    dim3 gdw(8, 32, 256);
    k_dw3x3<<<gdw, 256, 0, stream>>>(b2, wqdw,         out);
    k_dw3x3<<<gdw, 256, 0, stream>>>(b0, wkvdw,        b2);
    k_dw3x3<<<gdw, 256, 0, stream>>>(b1, wkvdw + 64*9, b0);

    k_qk_dots<<<256, 256, 0, stream>>>(out, b2, dots, sqq, sqk);
    k_softmax<<<1, 256, 0, stream>>>(dots, sqq, sqk, temp, attn);

    // attn@v + proj + residual -> x1_bf, y_bf (NHWC bf16)
    k_attnv_proj<<<1024, 256, 0, stream>>>(b0, x, attn, wproj, ln2w, ln2b,
                                           x1_bf, y_bf);

    // SFM: 5 MFMA convs. Wt taps: [0]=wadd1 [1]=wadd2 [2]=wmul1 [3]=wfuse
    dim3 gc(2, 128, 4);
    k_conv3x3_mfma<0><<<gc, 256, 0, stream>>>(y_bf, Wt + 0*36864, t_bf,
                                              nullptr, nullptr, nullptr);     // t1
    k_conv3x3_mfma<1><<<gc, 256, 0, stream>>>(t_bf, Wt + 1*36864, xadd_bf,
                                              nullptr, nullptr, nullptr);     // x_add
    k_conv3x3_mfma<0><<<gc, 256, 0, stream>>>(y_bf, Wt + 2*36864, t_bf,
                                              nullptr, nullptr, nullptr);     // t2
    k_conv3x3_mfma<2><<<gc, 256, 0, stream>>>(t_bf, Wt + 2*36864, z_bf,
                                              y_bf, xadd_bf, nullptr);        // z
    k_conv3x3_mfma<3><<<gc, 256, 0, stream>>>(z_bf, Wt + 3*36864, nullptr,
                                              x1_bf, nullptr, out);           // out
}